// Round 4
// baseline (948.904 us; speedup 1.0000x reference)
//
#include <hip/hip_runtime.h>
#include <math.h>

#define IN_F 1433
#define HID  16
#define OUTC 7
#define SCAN_T 1024

// ---------------------------------------------------------------------------
// zero_i32: replaces hipMemsetAsync for small buffers — the rocclr
// fillBufferAligned kernel costs ~335us inside graph replay for a 400KB fill.
// ---------------------------------------------------------------------------
__global__ __launch_bounds__(256) void zero_i32(int4* __restrict__ p, int n4)
{
    int i = blockIdx.x * blockDim.x + threadIdx.x;
    if (i < n4) p[i] = make_int4(0, 0, 0, 0);
}

// ---------------------------------------------------------------------------
// K1: XW = x @ W1   (N x 1433) @ (1433 x 16) -> (N x 16)
// Lane decomposition: lane = j4*16 + ks. 16 ks-lanes split K, 4 j4-groups
// each own 4 output columns. acc[4][4] per lane (4 rows/wave),
// 20 independent loads per iteration, 64-shuffle epilogue.
// ---------------------------------------------------------------------------
__global__ __launch_bounds__(256) void gcn_k1_xw(
    const float* __restrict__ x, const float* __restrict__ W1,
    float* __restrict__ XW, int N)
{
    const int wave = threadIdx.x >> 6;
    const int lane = threadIdx.x & 63;
    const int ks   = lane & 15;   // k-slice within wave
    const int j4   = lane >> 4;   // owns output cols j4*4 .. j4*4+3
    const int row0 = (blockIdx.x * 4 + wave) * 4;
    if (row0 >= N) return;

    const float* xr[4];
#pragma unroll
    for (int r = 0; r < 4; ++r) {
        int row = row0 + r; if (row > N - 1) row = N - 1;  // clamp, mask at write
        xr[r] = x + (size_t)row * IN_F;
    }
    const float4* W1v = (const float4*)W1;

    float acc[4][4];
#pragma unroll
    for (int r = 0; r < 4; ++r)
#pragma unroll
        for (int c = 0; c < 4; ++c) acc[r][c] = 0.f;

    // k = it*64 + u*16 + ks ; 23*64 = 1472 >= 1433
#pragma unroll 1
    for (int it = 0; it < 23; ++it) {
        const int kb = it * 64 + ks;
#pragma unroll
        for (int u = 0; u < 4; ++u) {
            const int k  = kb + u * 16;
            const bool ok = (k < IN_F);
            const int kk = ok ? k : (IN_F - 1);
            const float4 w = W1v[kk * 4 + j4];
            float xv[4];
#pragma unroll
            for (int r = 0; r < 4; ++r) xv[r] = ok ? xr[r][k] : 0.f;
#pragma unroll
            for (int r = 0; r < 4; ++r) {
                acc[r][0] += xv[r] * w.x;
                acc[r][1] += xv[r] * w.y;
                acc[r][2] += xv[r] * w.z;
                acc[r][3] += xv[r] * w.w;
            }
        }
    }

    // reduce over the 16 ks-lanes (lane bits 0..3)
#pragma unroll
    for (int m = 1; m <= 8; m <<= 1)
#pragma unroll
        for (int r = 0; r < 4; ++r)
#pragma unroll
            for (int c = 0; c < 4; ++c)
                acc[r][c] += __shfl_xor(acc[r][c], m);

    if (ks < 4) {
        const int row = row0 + ks;
        if (row < N) {
            float4 o;   // static-index selects (no runtime register indexing)
            o.x = (ks==0)?acc[0][0]:(ks==1)?acc[1][0]:(ks==2)?acc[2][0]:acc[3][0];
            o.y = (ks==0)?acc[0][1]:(ks==1)?acc[1][1]:(ks==2)?acc[2][1]:acc[3][1];
            o.z = (ks==0)?acc[0][2]:(ks==1)?acc[1][2]:(ks==2)?acc[2][2]:acc[3][2];
            o.w = (ks==0)?acc[0][3]:(ks==1)?acc[1][3]:(ks==2)?acc[2][3]:acc[3][3];
            *(float4*)(XW + (size_t)row * HID + j4 * 4) = o;
        }
    }
}

// ---------------------------------------------------------------------------
// CSR build: histogram -> single-block scan -> scatter (packed col+val)
// ---------------------------------------------------------------------------
__global__ __launch_bounds__(256) void csr_hist(
    const int* __restrict__ arow, int* __restrict__ cnt, int E)
{
    int e = blockIdx.x * blockDim.x + threadIdx.x;
    if (e < E) atomicAdd(&cnt[arow[e]], 1);
}

__global__ __launch_bounds__(SCAN_T) void csr_scan(
    const int* __restrict__ cnt, int* __restrict__ rowptr,
    int* __restrict__ cursor, int N)
{
    __shared__ int sums[SCAN_T];
    const int t = threadIdx.x;
    const int chunk = (N + SCAN_T - 1) / SCAN_T;
    const int lo = t * chunk;
    const int hi = min(lo + chunk, N);
    int s = 0;
    for (int i = lo; i < hi; ++i) s += cnt[i];
    sums[t] = s;
    __syncthreads();
    for (int d = 1; d < SCAN_T; d <<= 1) {
        int a = sums[t];
        int b = (t >= d) ? sums[t - d] : 0;
        __syncthreads();
        sums[t] = a + b;
        __syncthreads();
    }
    int run = sums[t] - s;  // exclusive prefix of this chunk
    for (int i = lo; i < hi; ++i) {
        rowptr[i] = run;
        cursor[i] = run;
        run += cnt[i];
    }
    if (t == SCAN_T - 1) rowptr[N] = sums[SCAN_T - 1];
}

__global__ __launch_bounds__(256) void csr_scatter(
    const int* __restrict__ arow, const int* __restrict__ acol,
    const float* __restrict__ aval, int* __restrict__ cursor,
    int2* __restrict__ ecv, int E)
{
    int e = blockIdx.x * blockDim.x + threadIdx.x;
    if (e >= E) return;
    const int r = arow[e];
    const int pos = atomicAdd(&cursor[r], 1);
    ecv[pos] = make_int2(acol[e], __float_as_int(aval[e]));
}

// ---------------------------------------------------------------------------
// SpMM(16) + relu(.+b1) @ W2 fused: one wave per row.
// lane = w*16 + j : 16 j-lanes = columns of XW, 4 w-ways split the edges.
// ---------------------------------------------------------------------------
__global__ __launch_bounds__(256) void spmm16_h2(
    const int* __restrict__ rowptr, const int2* __restrict__ ecv,
    const float* __restrict__ XW, const float* __restrict__ b1,
    const float* __restrict__ W2, float* __restrict__ h2, int N)
{
    const int gw = (int)((blockIdx.x * (size_t)blockDim.x + threadIdx.x) >> 6);
    if (gw >= N) return;
    const int lane = threadIdx.x & 63;
    const int j = lane & 15;
    const int w = lane >> 4;
    const int s = rowptr[gw], e = rowptr[gw + 1];

    float acc = 0.f;
    int k = s + w;
    while (k + 4 < e) {
        int2 a = ecv[k], b = ecv[k + 4];
        acc += __int_as_float(a.y) * XW[(size_t)a.x * HID + j];
        acc += __int_as_float(b.y) * XW[(size_t)b.x * HID + j];
        k += 8;
    }
    if (k < e) {
        int2 a = ecv[k];
        acc += __int_as_float(a.y) * XW[(size_t)a.x * HID + j];
    }
    // reduce the 4 edge-ways (lane bits 4,5)
    acc += __shfl_xor(acc, 16);
    acc += __shfl_xor(acc, 32);

    // fused layer-2 projection: h = relu(acc + b1[j]); p = h * W2[j][:]
    const float h = fmaxf(acc + b1[j], 0.f);
    float p[OUTC];
#pragma unroll
    for (int c = 0; c < OUTC; ++c) p[c] = h * W2[j * OUTC + c];
#pragma unroll
    for (int m = 1; m <= 8; m <<= 1)
#pragma unroll
        for (int c = 0; c < OUTC; ++c) p[c] += __shfl_xor(p[c], m);

    if (lane < 8) {
        float o = p[0];
        o = (lane == 1) ? p[1] : o;
        o = (lane == 2) ? p[2] : o;
        o = (lane == 3) ? p[3] : o;
        o = (lane == 4) ? p[4] : o;
        o = (lane == 5) ? p[5] : o;
        o = (lane == 6) ? p[6] : o;
        if (lane == 7) o = 0.f;           // pad col
        h2[(size_t)gw * 8 + lane] = o;
    }
}

// ---------------------------------------------------------------------------
// SpMM(7, stride-8 h2) + fused log_softmax: one wave per row.
// lane = w*8 + j : 8 j-lanes = classes (+pad), 8 w-ways split the edges.
// ---------------------------------------------------------------------------
__global__ __launch_bounds__(256) void spmm7_lsm(
    const int* __restrict__ rowptr, const int2* __restrict__ ecv,
    const float* __restrict__ h2, const float* __restrict__ b2,
    float* __restrict__ out, int N)
{
    const int gw = (int)((blockIdx.x * (size_t)blockDim.x + threadIdx.x) >> 6);
    if (gw >= N) return;
    const int lane = threadIdx.x & 63;
    const int j = lane & 7;
    const int w = lane >> 3;
    const int s = rowptr[gw], e = rowptr[gw + 1];

    float acc = 0.f;
    int k = s + w;
    while (k + 8 < e) {
        int2 a = ecv[k], b = ecv[k + 8];
        acc += __int_as_float(a.y) * h2[(size_t)a.x * 8 + j];
        acc += __int_as_float(b.y) * h2[(size_t)b.x * 8 + j];
        k += 16;
    }
    if (k < e) {
        int2 a = ecv[k];
        acc += __int_as_float(a.y) * h2[(size_t)a.x * 8 + j];
    }
    // reduce the 8 edge-ways (lane bits 3,4,5)
    acc += __shfl_xor(acc, 8);
    acc += __shfl_xor(acc, 16);
    acc += __shfl_xor(acc, 32);

    const float bias = b2[(j < OUTC) ? j : 0];
    const float val  = acc + bias;                 // j==7 masked below
    float mx = (j < OUTC) ? val : -INFINITY;
    mx = fmaxf(mx, __shfl_xor(mx, 1));
    mx = fmaxf(mx, __shfl_xor(mx, 2));
    mx = fmaxf(mx, __shfl_xor(mx, 4));
    float ex = (j < OUTC) ? expf(val - mx) : 0.f;
    ex += __shfl_xor(ex, 1);
    ex += __shfl_xor(ex, 2);
    ex += __shfl_xor(ex, 4);
    if (lane < OUTC) out[(size_t)gw * OUTC + lane] = val - mx - logf(ex);
}

// ---------------------------------------------------------------------------
// Fallback path kernels (atomic-based, used only if ws too small)
// ---------------------------------------------------------------------------
__global__ __launch_bounds__(256) void gcn_k2_spmm16_atomic(
    const int* __restrict__ arow, const int* __restrict__ acol,
    const float* __restrict__ aval, const float* __restrict__ XW,
    float* __restrict__ H, int E)
{
    int e = blockIdx.x * blockDim.x + threadIdx.x;
    if (e >= E) return;
    const int r = arow[e], c = acol[e];
    const float v = aval[e];
    const float4* src = (const float4*)(XW + (size_t)c * HID);
    float4 a = src[0], b = src[1], cc = src[2], d = src[3];
    float* dst = H + (size_t)r * HID;
    atomicAdd(dst + 0,  v * a.x);  atomicAdd(dst + 1,  v * a.y);
    atomicAdd(dst + 2,  v * a.z);  atomicAdd(dst + 3,  v * a.w);
    atomicAdd(dst + 4,  v * b.x);  atomicAdd(dst + 5,  v * b.y);
    atomicAdd(dst + 6,  v * b.z);  atomicAdd(dst + 7,  v * b.w);
    atomicAdd(dst + 8,  v * cc.x); atomicAdd(dst + 9,  v * cc.y);
    atomicAdd(dst + 10, v * cc.z); atomicAdd(dst + 11, v * cc.w);
    atomicAdd(dst + 12, v * d.x);  atomicAdd(dst + 13, v * d.y);
    atomicAdd(dst + 14, v * d.z);  atomicAdd(dst + 15, v * d.w);
}

__global__ __launch_bounds__(256) void gcn_k3_h2(
    const float* __restrict__ H, const float* __restrict__ b1,
    const float* __restrict__ W2, float* __restrict__ h2, int N)
{
    __shared__ float sW2[HID * OUTC];
    __shared__ float sb1[HID];
    if (threadIdx.x < HID * OUTC) sW2[threadIdx.x] = W2[threadIdx.x];
    if (threadIdx.x < HID)        sb1[threadIdx.x] = b1[threadIdx.x];
    __syncthreads();

    int row = blockIdx.x * blockDim.x + threadIdx.x;
    if (row >= N) return;

    const float4* hp = (const float4*)(H + (size_t)row * HID);
    float4 h0 = hp[0], h1 = hp[1], h2v = hp[2], h3 = hp[3];
    float h[16] = {h0.x, h0.y, h0.z, h0.w, h1.x, h1.y, h1.z, h1.w,
                   h2v.x, h2v.y, h2v.z, h2v.w, h3.x, h3.y, h3.z, h3.w};
#pragma unroll
    for (int i = 0; i < HID; ++i) {
        h[i] += sb1[i];
        h[i] = h[i] > 0.f ? h[i] : 0.f;
    }
    float o[8];
#pragma unroll
    for (int jj = 0; jj < OUTC; ++jj) {
        float sum = 0.f;
#pragma unroll
        for (int i = 0; i < HID; ++i) sum += h[i] * sW2[i * OUTC + jj];
        o[jj] = sum;
    }
    o[7] = 0.f;
    float4* op = (float4*)(h2 + (size_t)row * 8);
    op[0] = make_float4(o[0], o[1], o[2], o[3]);
    op[1] = make_float4(o[4], o[5], o[6], o[7]);
}

__global__ __launch_bounds__(256) void gcn_k4_spmm7_atomic(
    const int* __restrict__ arow, const int* __restrict__ acol,
    const float* __restrict__ aval, const float* __restrict__ h2,
    float* __restrict__ out, int E)
{
    int e = blockIdx.x * blockDim.x + threadIdx.x;
    if (e >= E) return;
    const int r = arow[e], c = acol[e];
    const float v = aval[e];
    const float* src = h2 + (size_t)c * 8;
    float* dst = out + (size_t)r * OUTC;
#pragma unroll
    for (int jj = 0; jj < OUTC; ++jj) atomicAdd(dst + jj, v * src[jj]);
}

__global__ __launch_bounds__(256) void gcn_k5_lsm(
    float* __restrict__ out, const float* __restrict__ b2, int N)
{
    int row = blockIdx.x * blockDim.x + threadIdx.x;
    if (row >= N) return;
    float* p = out + (size_t)row * OUTC;
    float v[OUTC];
#pragma unroll
    for (int jj = 0; jj < OUTC; ++jj) v[jj] = p[jj] + b2[jj];
    float m = v[0];
#pragma unroll
    for (int jj = 1; jj < OUTC; ++jj) m = fmaxf(m, v[jj]);
    float s = 0.f;
#pragma unroll
    for (int jj = 0; jj < OUTC; ++jj) s += expf(v[jj] - m);
    const float ls = logf(s);
#pragma unroll
    for (int jj = 0; jj < OUTC; ++jj) p[jj] = v[jj] - m - ls;
}

// ---------------------------------------------------------------------------
extern "C" void kernel_launch(void* const* d_in, const int* in_sizes, int n_in,
                              void* d_out, int out_size, void* d_ws, size_t ws_size,
                              hipStream_t stream)
{
    const float* x    = (const float*)d_in[0];
    const int*   arow = (const int*)d_in[1];
    const int*   acol = (const int*)d_in[2];
    const float* aval = (const float*)d_in[3];
    const float* W1   = (const float*)d_in[4];
    const float* b1   = (const float*)d_in[5];
    const float* W2   = (const float*)d_in[6];
    const float* b2   = (const float*)d_in[7];
    float* out = (float*)d_out;

    const int N = in_sizes[0] / IN_F;
    const int E = in_sizes[1];

    // fast-path ws layout: [ecv E*8] [XW N*16f] [h2 N*8f] [cnt N(pad4)] [cursor N] [rowptr N+1]
    const int Np4 = (N + 3) & ~3;   // cnt padded to int4 multiple for zero_i32
    char* wsp = (char*)d_ws;
    int2*  ecv    = (int2*)wsp;   wsp += (size_t)E * 8;
    float* XW     = (float*)wsp;  wsp += (size_t)N * HID * 4;
    float* h2     = (float*)wsp;  wsp += (size_t)N * 8 * 4;
    int*   cnt    = (int*)wsp;    wsp += (size_t)Np4 * 4;
    int*   cursor = (int*)wsp;    wsp += (size_t)N * 4;
    int*   rowptr = (int*)wsp;    wsp += (size_t)(N + 1) * 4;
    const size_t need = (size_t)(wsp - (char*)d_ws);

    const int eb = (E + 255) / 256;
    const int nb = (N + 255) / 256;

    if (ws_size >= need) {
        // ---- fast path: CSR + gather SpMM, no fp atomics, K3 fused ----
        const int n4 = Np4 / 4;
        zero_i32<<<(n4 + 255) / 256, 256, 0, stream>>>((int4*)cnt, n4);
        csr_hist<<<eb, 256, 0, stream>>>(arow, cnt, E);
        csr_scan<<<1, SCAN_T, 0, stream>>>(cnt, rowptr, cursor, N);
        csr_scatter<<<eb, 256, 0, stream>>>(arow, acol, aval, cursor, ecv, E);

        gcn_k1_xw<<<(N + 15) / 16, 256, 0, stream>>>(x, W1, XW, N);
        spmm16_h2<<<(N + 3) / 4, 256, 0, stream>>>(rowptr, ecv, XW, b1, W2, h2, N);
        spmm7_lsm<<<(N + 3) / 4, 256, 0, stream>>>(rowptr, ecv, h2, b2, out, N);
    } else {
        // ---- fallback: atomic path (needs only XW+H = 12.8 MB) ----
        float* XWf = (float*)d_ws;
        float* Hf  = XWf + (size_t)N * HID;
        float* h2f = XWf;   // XW dead after spmm16_atomic
        const int hz4 = (int)(((size_t)N * HID) / 4);
        zero_i32<<<(hz4 + 255) / 256, 256, 0, stream>>>((int4*)Hf, hz4);
        hipMemsetAsync(out, 0, (size_t)N * OUTC * sizeof(float), stream);
        gcn_k1_xw<<<(N + 15) / 16, 256, 0, stream>>>(x, W1, XWf, N);
        gcn_k2_spmm16_atomic<<<eb, 256, 0, stream>>>(arow, acol, aval, XWf, Hf, E);
        gcn_k3_h2<<<nb, 256, 0, stream>>>(Hf, b1, W2, h2f, N);
        gcn_k4_spmm7_atomic<<<eb, 256, 0, stream>>>(arow, acol, aval, h2f, out, E);
        gcn_k5_lsm<<<nb, 256, 0, stream>>>(out, b2, N);
    }
}

// Round 5
// 863.036 us; speedup vs baseline: 1.0995x; 1.0995x over previous
//
#include <hip/hip_runtime.h>
#include <math.h>

#define IN_F 1433
#define HID  16
#define OUTC 7
#define SCAN_T 1024

// ---------------------------------------------------------------------------
// zero_i32: cheap in-graph zeroing (rocclr fillBuffer not used)
// ---------------------------------------------------------------------------
__global__ __launch_bounds__(256) void zero_i32(int4* __restrict__ p, int n4)
{
    int i = blockIdx.x * blockDim.x + threadIdx.x;
    if (i < n4) p[i] = make_int4(0, 0, 0, 0);
}

// ---------------------------------------------------------------------------
// K1 v3: XW = x @ W1   (N x 1433) @ (1433 x 16) -> (N x 16)
// 4 rows/wave. Lane owns k = it*256 + lane*4 .. +3 (6 K-rounds total).
// Per round: 16 scalar x loads + 16 float4 W1 loads (256B contiguous/lane),
// 256 FMAs. acc[4][16]/lane, full butterfly, static-select write.
// ---------------------------------------------------------------------------
__global__ __launch_bounds__(256) void gcn_k1_xw(
    const float* __restrict__ x, const float* __restrict__ W1,
    float* __restrict__ XW, int N)
{
    const int wave = threadIdx.x >> 6;
    const int lane = threadIdx.x & 63;
    const int row0 = (blockIdx.x * 4 + wave) * 4;
    if (row0 >= N) return;

    const float* xr0 = x + (size_t)((row0 + 0 < N) ? row0 + 0 : N - 1) * IN_F;
    const float* xr1 = x + (size_t)((row0 + 1 < N) ? row0 + 1 : N - 1) * IN_F;
    const float* xr2 = x + (size_t)((row0 + 2 < N) ? row0 + 2 : N - 1) * IN_F;
    const float* xr3 = x + (size_t)((row0 + 3 < N) ? row0 + 3 : N - 1) * IN_F;
    const float4* W1v = (const float4*)W1;   // W1v[k*4+q] = W1[k][4q..4q+3]

    float acc[4][16];
#pragma unroll
    for (int r = 0; r < 4; ++r)
#pragma unroll
        for (int j = 0; j < 16; ++j) acc[r][j] = 0.f;

    // main rounds: it = 0..4  (k < 1280 < 1433, no bounds checks)
#pragma unroll 1
    for (int it = 0; it < 5; ++it) {
        const int k0 = it * 256 + lane * 4;
        float4 w[4][4];
#pragma unroll
        for (int kk = 0; kk < 4; ++kk)
#pragma unroll
            for (int q = 0; q < 4; ++q)
                w[kk][q] = W1v[(size_t)(k0 + kk) * 4 + q];
        float xv0[4], xv1[4], xv2[4], xv3[4];
#pragma unroll
        for (int kk = 0; kk < 4; ++kk) {
            xv0[kk] = xr0[k0 + kk];
            xv1[kk] = xr1[k0 + kk];
            xv2[kk] = xr2[k0 + kk];
            xv3[kk] = xr3[k0 + kk];
        }
#pragma unroll
        for (int kk = 0; kk < 4; ++kk) {
#pragma unroll
            for (int q = 0; q < 4; ++q) {
                acc[0][q*4+0] += xv0[kk] * w[kk][q].x;
                acc[0][q*4+1] += xv0[kk] * w[kk][q].y;
                acc[0][q*4+2] += xv0[kk] * w[kk][q].z;
                acc[0][q*4+3] += xv0[kk] * w[kk][q].w;
                acc[1][q*4+0] += xv1[kk] * w[kk][q].x;
                acc[1][q*4+1] += xv1[kk] * w[kk][q].y;
                acc[1][q*4+2] += xv1[kk] * w[kk][q].z;
                acc[1][q*4+3] += xv1[kk] * w[kk][q].w;
                acc[2][q*4+0] += xv2[kk] * w[kk][q].x;
                acc[2][q*4+1] += xv2[kk] * w[kk][q].y;
                acc[2][q*4+2] += xv2[kk] * w[kk][q].z;
                acc[2][q*4+3] += xv2[kk] * w[kk][q].w;
                acc[3][q*4+0] += xv3[kk] * w[kk][q].x;
                acc[3][q*4+1] += xv3[kk] * w[kk][q].y;
                acc[3][q*4+2] += xv3[kk] * w[kk][q].z;
                acc[3][q*4+3] += xv3[kk] * w[kk][q].w;
            }
        }
    }

    // tail round: it = 5, k = 1280 + lane*4 + kk, masked
    {
        const int k0 = 1280 + lane * 4;
        float4 w[4][4];
        float xv0[4], xv1[4], xv2[4], xv3[4];
#pragma unroll
        for (int kk = 0; kk < 4; ++kk) {
            const int k  = k0 + kk;
            const bool ok = (k < IN_F);
            const int kcl = ok ? k : (IN_F - 1);
#pragma unroll
            for (int q = 0; q < 4; ++q) w[kk][q] = W1v[(size_t)kcl * 4 + q];
            xv0[kk] = ok ? xr0[k] : 0.f;
            xv1[kk] = ok ? xr1[k] : 0.f;
            xv2[kk] = ok ? xr2[k] : 0.f;
            xv3[kk] = ok ? xr3[k] : 0.f;
        }
#pragma unroll
        for (int kk = 0; kk < 4; ++kk) {
#pragma unroll
            for (int q = 0; q < 4; ++q) {
                acc[0][q*4+0] += xv0[kk] * w[kk][q].x;
                acc[0][q*4+1] += xv0[kk] * w[kk][q].y;
                acc[0][q*4+2] += xv0[kk] * w[kk][q].z;
                acc[0][q*4+3] += xv0[kk] * w[kk][q].w;
                acc[1][q*4+0] += xv1[kk] * w[kk][q].x;
                acc[1][q*4+1] += xv1[kk] * w[kk][q].y;
                acc[1][q*4+2] += xv1[kk] * w[kk][q].z;
                acc[1][q*4+3] += xv1[kk] * w[kk][q].w;
                acc[2][q*4+0] += xv2[kk] * w[kk][q].x;
                acc[2][q*4+1] += xv2[kk] * w[kk][q].y;
                acc[2][q*4+2] += xv2[kk] * w[kk][q].z;
                acc[2][q*4+3] += xv2[kk] * w[kk][q].w;
                acc[3][q*4+0] += xv3[kk] * w[kk][q].x;
                acc[3][q*4+1] += xv3[kk] * w[kk][q].y;
                acc[3][q*4+2] += xv3[kk] * w[kk][q].z;
                acc[3][q*4+3] += xv3[kk] * w[kk][q].w;
            }
        }
    }

    // full 64-lane butterfly: every lane ends with the total
#pragma unroll
    for (int m = 1; m <= 32; m <<= 1)
#pragma unroll
        for (int r = 0; r < 4; ++r)
#pragma unroll
            for (int j = 0; j < 16; ++j)
                acc[r][j] += __shfl_xor(acc[r][j], m);

    if (lane < 16) {
        const int r  = lane >> 2;
        const int j4 = lane & 3;
        const int row = row0 + r;
        if (row < N) {
#define SELJ(rr, c) (j4 == 0 ? acc[rr][0 + (c)] : j4 == 1 ? acc[rr][4 + (c)] \
                   : j4 == 2 ? acc[rr][8 + (c)] : acc[rr][12 + (c)])
#define PICK(c) (r == 0 ? SELJ(0, c) : r == 1 ? SELJ(1, c) \
               : r == 2 ? SELJ(2, c) : SELJ(3, c))
            float4 o;
            o.x = PICK(0); o.y = PICK(1); o.z = PICK(2); o.w = PICK(3);
#undef PICK
#undef SELJ
            *(float4*)(XW + (size_t)row * HID + j4 * 4) = o;
        }
    }
}

// ---------------------------------------------------------------------------
// CSR build: histogram -> single-block scan -> scatter (packed col+val)
// ---------------------------------------------------------------------------
__global__ __launch_bounds__(256) void csr_hist(
    const int* __restrict__ arow, int* __restrict__ cnt, int E)
{
    const int tid = blockIdx.x * blockDim.x + threadIdx.x;
    const int stride = gridDim.x * blockDim.x;
    const int E4 = E >> 2;
    const int4* a4 = (const int4*)arow;
    for (int v = tid; v < E4; v += stride) {
        int4 r = a4[v];
        atomicAdd(&cnt[r.x], 1);
        atomicAdd(&cnt[r.y], 1);
        atomicAdd(&cnt[r.z], 1);
        atomicAdd(&cnt[r.w], 1);
    }
    for (int v = E4 * 4 + tid; v < E; v += stride) atomicAdd(&cnt[arow[v]], 1);
}

__global__ __launch_bounds__(SCAN_T) void csr_scan(
    const int* __restrict__ cnt, int* __restrict__ rowptr,
    int* __restrict__ cursor, int N)
{
    __shared__ int sums[SCAN_T];
    const int t = threadIdx.x;
    const int chunk = (((N + SCAN_T - 1) / SCAN_T) + 3) & ~3;  // 4-aligned
    const int lo = t * chunk;
    int s = 0;
    const bool full = (lo + chunk <= N);
    if (full) {
        const int4* c4 = (const int4*)(cnt + lo);
#pragma unroll 4
        for (int i = 0; i < chunk / 4; ++i) {
            int4 v = c4[i];
            s += v.x + v.y + v.z + v.w;
        }
    } else {
        const int hi = (lo + chunk < N) ? lo + chunk : N;
        for (int i = lo; i < hi; ++i) s += cnt[i];
    }
    sums[t] = s;
    __syncthreads();
    for (int d = 1; d < SCAN_T; d <<= 1) {
        int a = sums[t];
        int b = (t >= d) ? sums[t - d] : 0;
        __syncthreads();
        sums[t] = a + b;
        __syncthreads();
    }
    int run = sums[t] - s;  // exclusive prefix of this chunk
    if (full) {
        const int4* c4 = (const int4*)(cnt + lo);
        int4* rp4 = (int4*)(rowptr + lo);
        int4* cu4 = (int4*)(cursor + lo);
        for (int i = 0; i < chunk / 4; ++i) {
            int4 v = c4[i];
            int4 o;
            o.x = run; run += v.x;
            o.y = run; run += v.y;
            o.z = run; run += v.z;
            o.w = run; run += v.w;
            rp4[i] = o;
            cu4[i] = o;
        }
    } else {
        const int hi = (lo + chunk < N) ? lo + chunk : N;
        for (int i = lo; i < hi; ++i) {
            rowptr[i] = run;
            cursor[i] = run;
            run += cnt[i];
        }
    }
    if (t == SCAN_T - 1) rowptr[N] = sums[SCAN_T - 1];
}

__global__ __launch_bounds__(256) void csr_scatter(
    const int* __restrict__ arow, const int* __restrict__ acol,
    const float* __restrict__ aval, int* __restrict__ cursor,
    int2* __restrict__ ecv, int E)
{
    const int tid = blockIdx.x * blockDim.x + threadIdx.x;
    const int stride = gridDim.x * blockDim.x;
    const int E4 = E >> 2;
    const int4*   ar4 = (const int4*)arow;
    const int4*   ac4 = (const int4*)acol;
    const float4* av4 = (const float4*)aval;
    for (int v = tid; v < E4; v += stride) {
        int4 r = ar4[v];
        int4 c = ac4[v];
        float4 val = av4[v];
        int p0 = atomicAdd(&cursor[r.x], 1);
        int p1 = atomicAdd(&cursor[r.y], 1);
        int p2 = atomicAdd(&cursor[r.z], 1);
        int p3 = atomicAdd(&cursor[r.w], 1);
        ecv[p0] = make_int2(c.x, __float_as_int(val.x));
        ecv[p1] = make_int2(c.y, __float_as_int(val.y));
        ecv[p2] = make_int2(c.z, __float_as_int(val.z));
        ecv[p3] = make_int2(c.w, __float_as_int(val.w));
    }
    for (int v = E4 * 4 + tid; v < E; v += stride) {
        int pos = atomicAdd(&cursor[arow[v]], 1);
        ecv[pos] = make_int2(acol[v], __float_as_int(aval[v]));
    }
}

// ---------------------------------------------------------------------------
// SpMM(16) + relu(.+b1) @ W2 fused: one wave per row, 4 edge-ways x 16 cols,
// 4-deep gather pipeline.
// ---------------------------------------------------------------------------
__global__ __launch_bounds__(256) void spmm16_h2(
    const int* __restrict__ rowptr, const int2* __restrict__ ecv,
    const float* __restrict__ XW, const float* __restrict__ b1,
    const float* __restrict__ W2, float* __restrict__ h2, int N)
{
    const int gw = (int)((blockIdx.x * (size_t)blockDim.x + threadIdx.x) >> 6);
    if (gw >= N) return;
    const int lane = threadIdx.x & 63;
    const int j = lane & 15;
    const int w = lane >> 4;
    const int s = rowptr[gw], e = rowptr[gw + 1];

    float acc = 0.f;
    int k = s + w;
    while (k + 12 < e) {
        int2 a0 = ecv[k], a1 = ecv[k + 4], a2 = ecv[k + 8], a3 = ecv[k + 12];
        float g0 = XW[(size_t)a0.x * HID + j];
        float g1 = XW[(size_t)a1.x * HID + j];
        float g2 = XW[(size_t)a2.x * HID + j];
        float g3 = XW[(size_t)a3.x * HID + j];
        acc += __int_as_float(a0.y) * g0;
        acc += __int_as_float(a1.y) * g1;
        acc += __int_as_float(a2.y) * g2;
        acc += __int_as_float(a3.y) * g3;
        k += 16;
    }
    if (k + 4 < e) {
        int2 a0 = ecv[k], a1 = ecv[k + 4];
        acc += __int_as_float(a0.y) * XW[(size_t)a0.x * HID + j];
        acc += __int_as_float(a1.y) * XW[(size_t)a1.x * HID + j];
        k += 8;
    }
    if (k < e) {
        int2 a0 = ecv[k];
        acc += __int_as_float(a0.y) * XW[(size_t)a0.x * HID + j];
    }
    // reduce the 4 edge-ways (lane bits 4,5)
    acc += __shfl_xor(acc, 16);
    acc += __shfl_xor(acc, 32);

    // fused layer-2 projection: h = relu(acc + b1[j]); p = h * W2[j][:]
    const float h = fmaxf(acc + b1[j], 0.f);
    float p[OUTC];
#pragma unroll
    for (int c = 0; c < OUTC; ++c) p[c] = h * W2[j * OUTC + c];
#pragma unroll
    for (int m = 1; m <= 8; m <<= 1)
#pragma unroll
        for (int c = 0; c < OUTC; ++c) p[c] += __shfl_xor(p[c], m);

    if (lane < 8) {
        float o = p[0];
        o = (lane == 1) ? p[1] : o;
        o = (lane == 2) ? p[2] : o;
        o = (lane == 3) ? p[3] : o;
        o = (lane == 4) ? p[4] : o;
        o = (lane == 5) ? p[5] : o;
        o = (lane == 6) ? p[6] : o;
        if (lane == 7) o = 0.f;           // pad col
        h2[(size_t)gw * 8 + lane] = o;
    }
}

// ---------------------------------------------------------------------------
// SpMM(7, stride-8 h2) + fused log_softmax: one wave per row,
// 8 edge-ways x 8 cols, 4-deep gather pipeline.
// ---------------------------------------------------------------------------
__global__ __launch_bounds__(256) void spmm7_lsm(
    const int* __restrict__ rowptr, const int2* __restrict__ ecv,
    const float* __restrict__ h2, const float* __restrict__ b2,
    float* __restrict__ out, int N)
{
    const int gw = (int)((blockIdx.x * (size_t)blockDim.x + threadIdx.x) >> 6);
    if (gw >= N) return;
    const int lane = threadIdx.x & 63;
    const int j = lane & 7;
    const int w = lane >> 3;
    const int s = rowptr[gw], e = rowptr[gw + 1];

    float acc = 0.f;
    int k = s + w;
    while (k + 24 < e) {
        int2 a0 = ecv[k], a1 = ecv[k + 8], a2 = ecv[k + 16], a3 = ecv[k + 24];
        float g0 = h2[(size_t)a0.x * 8 + j];
        float g1 = h2[(size_t)a1.x * 8 + j];
        float g2 = h2[(size_t)a2.x * 8 + j];
        float g3 = h2[(size_t)a3.x * 8 + j];
        acc += __int_as_float(a0.y) * g0;
        acc += __int_as_float(a1.y) * g1;
        acc += __int_as_float(a2.y) * g2;
        acc += __int_as_float(a3.y) * g3;
        k += 32;
    }
    if (k + 8 < e) {
        int2 a0 = ecv[k], a1 = ecv[k + 8];
        acc += __int_as_float(a0.y) * h2[(size_t)a0.x * 8 + j];
        acc += __int_as_float(a1.y) * h2[(size_t)a1.x * 8 + j];
        k += 16;
    }
    if (k < e) {
        int2 a0 = ecv[k];
        acc += __int_as_float(a0.y) * h2[(size_t)a0.x * 8 + j];
    }
    // reduce the 8 edge-ways (lane bits 3,4,5)
    acc += __shfl_xor(acc, 8);
    acc += __shfl_xor(acc, 16);
    acc += __shfl_xor(acc, 32);

    const float bias = b2[(j < OUTC) ? j : 0];
    const float val  = acc + bias;                 // j==7 masked below
    float mx = (j < OUTC) ? val : -INFINITY;
    mx = fmaxf(mx, __shfl_xor(mx, 1));
    mx = fmaxf(mx, __shfl_xor(mx, 2));
    mx = fmaxf(mx, __shfl_xor(mx, 4));
    float ex = (j < OUTC) ? expf(val - mx) : 0.f;
    ex += __shfl_xor(ex, 1);
    ex += __shfl_xor(ex, 2);
    ex += __shfl_xor(ex, 4);
    if (lane < OUTC) out[(size_t)gw * OUTC + lane] = val - mx - logf(ex);
}

// ---------------------------------------------------------------------------
// Fallback path kernels (atomic-based, used only if ws too small)
// ---------------------------------------------------------------------------
__global__ __launch_bounds__(256) void gcn_k2_spmm16_atomic(
    const int* __restrict__ arow, const int* __restrict__ acol,
    const float* __restrict__ aval, const float* __restrict__ XW,
    float* __restrict__ H, int E)
{
    int e = blockIdx.x * blockDim.x + threadIdx.x;
    if (e >= E) return;
    const int r = arow[e], c = acol[e];
    const float v = aval[e];
    const float4* src = (const float4*)(XW + (size_t)c * HID);
    float4 a = src[0], b = src[1], cc = src[2], d = src[3];
    float* dst = H + (size_t)r * HID;
    atomicAdd(dst + 0,  v * a.x);  atomicAdd(dst + 1,  v * a.y);
    atomicAdd(dst + 2,  v * a.z);  atomicAdd(dst + 3,  v * a.w);
    atomicAdd(dst + 4,  v * b.x);  atomicAdd(dst + 5,  v * b.y);
    atomicAdd(dst + 6,  v * b.z);  atomicAdd(dst + 7,  v * b.w);
    atomicAdd(dst + 8,  v * cc.x); atomicAdd(dst + 9,  v * cc.y);
    atomicAdd(dst + 10, v * cc.z); atomicAdd(dst + 11, v * cc.w);
    atomicAdd(dst + 12, v * d.x);  atomicAdd(dst + 13, v * d.y);
    atomicAdd(dst + 14, v * d.z);  atomicAdd(dst + 15, v * d.w);
}

__global__ __launch_bounds__(256) void gcn_k3_h2(
    const float* __restrict__ H, const float* __restrict__ b1,
    const float* __restrict__ W2, float* __restrict__ h2, int N)
{
    __shared__ float sW2[HID * OUTC];
    __shared__ float sb1[HID];
    if (threadIdx.x < HID * OUTC) sW2[threadIdx.x] = W2[threadIdx.x];
    if (threadIdx.x < HID)        sb1[threadIdx.x] = b1[threadIdx.x];
    __syncthreads();

    int row = blockIdx.x * blockDim.x + threadIdx.x;
    if (row >= N) return;

    const float4* hp = (const float4*)(H + (size_t)row * HID);
    float4 h0 = hp[0], h1 = hp[1], h2v = hp[2], h3 = hp[3];
    float h[16] = {h0.x, h0.y, h0.z, h0.w, h1.x, h1.y, h1.z, h1.w,
                   h2v.x, h2v.y, h2v.z, h2v.w, h3.x, h3.y, h3.z, h3.w};
#pragma unroll
    for (int i = 0; i < HID; ++i) {
        h[i] += sb1[i];
        h[i] = h[i] > 0.f ? h[i] : 0.f;
    }
    float o[8];
#pragma unroll
    for (int jj = 0; jj < OUTC; ++jj) {
        float sum = 0.f;
#pragma unroll
        for (int i = 0; i < HID; ++i) sum += h[i] * sW2[i * OUTC + jj];
        o[jj] = sum;
    }
    o[7] = 0.f;
    float4* op = (float4*)(h2 + (size_t)row * 8);
    op[0] = make_float4(o[0], o[1], o[2], o[3]);
    op[1] = make_float4(o[4], o[5], o[6], o[7]);
}

__global__ __launch_bounds__(256) void gcn_k4_spmm7_atomic(
    const int* __restrict__ arow, const int* __restrict__ acol,
    const float* __restrict__ aval, const float* __restrict__ h2,
    float* __restrict__ out, int E)
{
    int e = blockIdx.x * blockDim.x + threadIdx.x;
    if (e >= E) return;
    const int r = arow[e], c = acol[e];
    const float v = aval[e];
    const float* src = h2 + (size_t)c * 8;
    float* dst = out + (size_t)r * OUTC;
#pragma unroll
    for (int jj = 0; jj < OUTC; ++jj) atomicAdd(dst + jj, v * src[jj]);
}

__global__ __launch_bounds__(256) void gcn_k5_lsm(
    float* __restrict__ out, const float* __restrict__ b2, int N)
{
    int row = blockIdx.x * blockDim.x + threadIdx.x;
    if (row >= N) return;
    float* p = out + (size_t)row * OUTC;
    float v[OUTC];
#pragma unroll
    for (int jj = 0; jj < OUTC; ++jj) v[jj] = p[jj] + b2[jj];
    float m = v[0];
#pragma unroll
    for (int jj = 1; jj < OUTC; ++jj) m = fmaxf(m, v[jj]);
    float s = 0.f;
#pragma unroll
    for (int jj = 0; jj < OUTC; ++jj) s += expf(v[jj] - m);
    const float ls = logf(s);
#pragma unroll
    for (int jj = 0; jj < OUTC; ++jj) p[jj] = v[jj] - m - ls;
}

// ---------------------------------------------------------------------------
extern "C" void kernel_launch(void* const* d_in, const int* in_sizes, int n_in,
                              void* d_out, int out_size, void* d_ws, size_t ws_size,
                              hipStream_t stream)
{
    const float* x    = (const float*)d_in[0];
    const int*   arow = (const int*)d_in[1];
    const int*   acol = (const int*)d_in[2];
    const float* aval = (const float*)d_in[3];
    const float* W1   = (const float*)d_in[4];
    const float* b1   = (const float*)d_in[5];
    const float* W2   = (const float*)d_in[6];
    const float* b2   = (const float*)d_in[7];
    float* out = (float*)d_out;

    const int N = in_sizes[0] / IN_F;
    const int E = in_sizes[1];

    // fast-path ws layout (all chunks 16B-aligned):
    // [ecv E*8] [XW N*16f] [h2 N*8f] [cnt Np4] [cursor Np4] [rowptr Np4+4]
    const int Np4 = (N + 3) & ~3;
    char* wsp = (char*)d_ws;
    int2*  ecv    = (int2*)wsp;   wsp += (size_t)E * 8;
    float* XW     = (float*)wsp;  wsp += (size_t)N * HID * 4;
    float* h2     = (float*)wsp;  wsp += (size_t)N * 8 * 4;
    int*   cnt    = (int*)wsp;    wsp += (size_t)Np4 * 4;
    int*   cursor = (int*)wsp;    wsp += (size_t)Np4 * 4;
    int*   rowptr = (int*)wsp;    wsp += (size_t)(Np4 + 4) * 4;
    const size_t need = (size_t)(wsp - (char*)d_ws);

    const int eb = (E + 255) / 256;
    const int nb = (N + 255) / 256;

    if (ws_size >= need) {
        // ---- fast path: CSR + gather SpMM, no fp atomics, K3 fused ----
        const int n4 = Np4 / 4;
        zero_i32<<<(n4 + 255) / 256, 256, 0, stream>>>((int4*)cnt, n4);
        csr_hist<<<2048, 256, 0, stream>>>(arow, cnt, E);
        csr_scan<<<1, SCAN_T, 0, stream>>>(cnt, rowptr, cursor, N);
        csr_scatter<<<2048, 256, 0, stream>>>(arow, acol, aval, cursor, ecv, E);

        gcn_k1_xw<<<(N + 15) / 16, 256, 0, stream>>>(x, W1, XW, N);
        spmm16_h2<<<(N + 3) / 4, 256, 0, stream>>>(rowptr, ecv, XW, b1, W2, h2, N);
        spmm7_lsm<<<(N + 3) / 4, 256, 0, stream>>>(rowptr, ecv, h2, b2, out, N);
    } else {
        // ---- fallback: atomic path (needs only XW+H = 12.8 MB) ----
        float* XWf = (float*)d_ws;
        float* Hf  = XWf + (size_t)N * HID;
        float* h2f = XWf;   // XW dead after spmm16_atomic
        const int hz4 = (int)(((size_t)N * HID) / 4);
        zero_i32<<<(hz4 + 255) / 256, 256, 0, stream>>>((int4*)Hf, hz4);
        hipMemsetAsync(out, 0, (size_t)N * OUTC * sizeof(float), stream);
        gcn_k1_xw<<<(N + 15) / 16, 256, 0, stream>>>(x, W1, XWf, N);
        gcn_k2_spmm16_atomic<<<eb, 256, 0, stream>>>(arow, acol, aval, XWf, Hf, E);
        gcn_k3_h2<<<nb, 256, 0, stream>>>(Hf, b1, W2, h2f, N);
        gcn_k4_spmm7_atomic<<<eb, 256, 0, stream>>>(arow, acol, aval, h2f, out, E);
        gcn_k5_lsm<<<nb, 256, 0, stream>>>(out, b2, N);
    }
}

// Round 6
// 745.233 us; speedup vs baseline: 1.2733x; 1.1581x over previous
//
#include <hip/hip_runtime.h>
#include <math.h>

#define IN_F 1433
#define HID  16
#define OUTC 7
#define SCAN_T 1024

// K1 geometry
#define K1_THREADS 512        // 8 waves
#define K1_ROWS_W  8          // rows per wave
#define K1_ROWS_B  64         // rows per block
#define KA         768        // phase-A k count (52224 B LDS)
#define LDSW       17         // padded LDS row stride (words)

// ---------------------------------------------------------------------------
// zero_i32: cheap in-graph zeroing
// ---------------------------------------------------------------------------
__global__ __launch_bounds__(256) void zero_i32(int4* __restrict__ p, int n4)
{
    int i = blockIdx.x * blockDim.x + threadIdx.x;
    if (i < n4) p[i] = make_int4(0, 0, 0, 0);
}

// ---------------------------------------------------------------------------
// K1 v4: XW = x @ W1  with W1 staged in LDS (two phases).
// lane = j4*16 + ks: 16 ks-lanes split k, j4 owns output cols j4*4..+3.
// Per 16-k chunk per lane: 4 ds_read_b32 (stride-17 rows, ~2-way) +
// 8 broadcast x loads (1 cache line each, fully used) + 32 FMA.
// acc[8][4]/lane; 4-step butterfly over ks; float4 stores.
// ---------------------------------------------------------------------------
__global__ __launch_bounds__(K1_THREADS) void gcn_k1_xw(
    const float* __restrict__ x, const float* __restrict__ W1,
    float* __restrict__ XW, int N)
{
    __shared__ float sW[KA * LDSW];   // 52224 B

    const int wave = threadIdx.x >> 6;
    const int lane = threadIdx.x & 63;
    const int ks   = lane & 15;
    const int j4   = lane >> 4;
    const int row0 = blockIdx.x * K1_ROWS_B + wave * K1_ROWS_W;
    // NOTE: no early return — __syncthreads below must see all waves.

    size_t xoff[K1_ROWS_W];
#pragma unroll
    for (int r = 0; r < K1_ROWS_W; ++r) {
        int row = row0 + r;
        if (row > N - 1) row = N - 1;       // clamp; store masked later
        xoff[r] = (size_t)row * IN_F;
    }

    float acc[K1_ROWS_W][4];
#pragma unroll
    for (int r = 0; r < K1_ROWS_W; ++r)
#pragma unroll
        for (int jj = 0; jj < 4; ++jj) acc[r][jj] = 0.f;

    // ---------------- phase A: k in [0, KA) ----------------
    for (int f = threadIdx.x; f < KA * HID; f += K1_THREADS)
        sW[(f >> 4) * LDSW + (f & 15)] = W1[f];
    __syncthreads();

#pragma unroll 2
    for (int c = 0; c < KA / 16; ++c) {
        const int kloc = c * 16 + ks;
        const float* wr = sW + (size_t)kloc * LDSW + j4 * 4;
        float w0 = wr[0], w1 = wr[1], w2 = wr[2], w3 = wr[3];
        const int k = kloc;                 // phase A: k == kloc
        float xv[K1_ROWS_W];
#pragma unroll
        for (int r = 0; r < K1_ROWS_W; ++r) xv[r] = x[xoff[r] + k];
#pragma unroll
        for (int r = 0; r < K1_ROWS_W; ++r) {
            acc[r][0] += xv[r] * w0;
            acc[r][1] += xv[r] * w1;
            acc[r][2] += xv[r] * w2;
            acc[r][3] += xv[r] * w3;
        }
    }
    __syncthreads();

    // ---------------- phase B: k in [KA, IN_F) ----------------
    for (int f = threadIdx.x; f < (IN_F - KA) * HID; f += K1_THREADS)
        sW[(f >> 4) * LDSW + (f & 15)] = W1[KA * HID + f];
    __syncthreads();

    const int NB_CHUNKS = (IN_F - KA + 15) / 16;   // 42, last partial
#pragma unroll 2
    for (int c = 0; c < NB_CHUNKS; ++c) {
        const int kloc = c * 16 + ks;              // < 672, in LDS bounds
        const int k = KA + kloc;
        const bool ok = (k < IN_F);
        const float* wr = sW + (size_t)kloc * LDSW + j4 * 4;
        float w0 = wr[0], w1 = wr[1], w2 = wr[2], w3 = wr[3];
        float xv[K1_ROWS_W];
#pragma unroll
        for (int r = 0; r < K1_ROWS_W; ++r)
            xv[r] = ok ? x[xoff[r] + k] : 0.f;     // 0 * stale-w == 0
#pragma unroll
        for (int r = 0; r < K1_ROWS_W; ++r) {
            acc[r][0] += xv[r] * w0;
            acc[r][1] += xv[r] * w1;
            acc[r][2] += xv[r] * w2;
            acc[r][3] += xv[r] * w3;
        }
    }

    // butterfly over the 16 ks-lanes (lane bits 0..3)
#pragma unroll
    for (int m = 1; m <= 8; m <<= 1)
#pragma unroll
        for (int r = 0; r < K1_ROWS_W; ++r)
#pragma unroll
            for (int jj = 0; jj < 4; ++jj)
                acc[r][jj] += __shfl_xor(acc[r][jj], m);

    if (ks == 0) {
#pragma unroll
        for (int r = 0; r < K1_ROWS_W; ++r) {
            const int row = row0 + r;
            if (row < N) {
                float4 o = make_float4(acc[r][0], acc[r][1], acc[r][2], acc[r][3]);
                *(float4*)(XW + (size_t)row * HID + j4 * 4) = o;
            }
        }
    }
}

// ---------------------------------------------------------------------------
// CSR build: histogram -> single-block scan -> scatter (packed col+val)
// ---------------------------------------------------------------------------
__global__ __launch_bounds__(256) void csr_hist(
    const int* __restrict__ arow, int* __restrict__ cnt, int E)
{
    const int tid = blockIdx.x * blockDim.x + threadIdx.x;
    const int stride = gridDim.x * blockDim.x;
    const int E4 = E >> 2;
    const int4* a4 = (const int4*)arow;
    for (int v = tid; v < E4; v += stride) {
        int4 r = a4[v];
        atomicAdd(&cnt[r.x], 1);
        atomicAdd(&cnt[r.y], 1);
        atomicAdd(&cnt[r.z], 1);
        atomicAdd(&cnt[r.w], 1);
    }
    for (int v = E4 * 4 + tid; v < E; v += stride) atomicAdd(&cnt[arow[v]], 1);
}

__global__ __launch_bounds__(SCAN_T) void csr_scan(
    const int* __restrict__ cnt, int* __restrict__ rowptr,
    int* __restrict__ cursor, int N)
{
    __shared__ int sums[SCAN_T];
    const int t = threadIdx.x;
    const int chunk = (((N + SCAN_T - 1) / SCAN_T) + 3) & ~3;  // 4-aligned
    const int lo = t * chunk;
    int s = 0;
    const bool full = (lo + chunk <= N);
    if (full) {
        const int4* c4 = (const int4*)(cnt + lo);
#pragma unroll 4
        for (int i = 0; i < chunk / 4; ++i) {
            int4 v = c4[i];
            s += v.x + v.y + v.z + v.w;
        }
    } else {
        const int hi = (lo + chunk < N) ? lo + chunk : N;
        for (int i = lo; i < hi; ++i) s += cnt[i];
    }
    sums[t] = s;
    __syncthreads();
    for (int d = 1; d < SCAN_T; d <<= 1) {
        int a = sums[t];
        int b = (t >= d) ? sums[t - d] : 0;
        __syncthreads();
        sums[t] = a + b;
        __syncthreads();
    }
    int run = sums[t] - s;  // exclusive prefix of this chunk
    if (full) {
        const int4* c4 = (const int4*)(cnt + lo);
        int4* rp4 = (int4*)(rowptr + lo);
        int4* cu4 = (int4*)(cursor + lo);
        for (int i = 0; i < chunk / 4; ++i) {
            int4 v = c4[i];
            int4 o;
            o.x = run; run += v.x;
            o.y = run; run += v.y;
            o.z = run; run += v.z;
            o.w = run; run += v.w;
            rp4[i] = o;
            cu4[i] = o;
        }
    } else {
        const int hi = (lo + chunk < N) ? lo + chunk : N;
        for (int i = lo; i < hi; ++i) {
            rowptr[i] = run;
            cursor[i] = run;
            run += cnt[i];
        }
    }
    if (t == SCAN_T - 1) rowptr[N] = sums[SCAN_T - 1];
}

__global__ __launch_bounds__(256) void csr_scatter(
    const int* __restrict__ arow, const int* __restrict__ acol,
    const float* __restrict__ aval, int* __restrict__ cursor,
    int2* __restrict__ ecv, int E)
{
    const int tid = blockIdx.x * blockDim.x + threadIdx.x;
    const int stride = gridDim.x * blockDim.x;
    const int E4 = E >> 2;
    const int4*   ar4 = (const int4*)arow;
    const int4*   ac4 = (const int4*)acol;
    const float4* av4 = (const float4*)aval;
    for (int v = tid; v < E4; v += stride) {
        int4 r = ar4[v];
        int4 c = ac4[v];
        float4 val = av4[v];
        int p0 = atomicAdd(&cursor[r.x], 1);
        int p1 = atomicAdd(&cursor[r.y], 1);
        int p2 = atomicAdd(&cursor[r.z], 1);
        int p3 = atomicAdd(&cursor[r.w], 1);
        ecv[p0] = make_int2(c.x, __float_as_int(val.x));
        ecv[p1] = make_int2(c.y, __float_as_int(val.y));
        ecv[p2] = make_int2(c.z, __float_as_int(val.z));
        ecv[p3] = make_int2(c.w, __float_as_int(val.w));
    }
    for (int v = E4 * 4 + tid; v < E; v += stride) {
        int pos = atomicAdd(&cursor[arow[v]], 1);
        ecv[pos] = make_int2(acol[v], __float_as_int(aval[v]));
    }
}

// ---------------------------------------------------------------------------
// SpMM(16) + relu(.+b1) @ W2 fused: one wave per row, 4 edge-ways x 16 cols.
// ---------------------------------------------------------------------------
__global__ __launch_bounds__(256) void spmm16_h2(
    const int* __restrict__ rowptr, const int2* __restrict__ ecv,
    const float* __restrict__ XW, const float* __restrict__ b1,
    const float* __restrict__ W2, float* __restrict__ h2, int N)
{
    const int gw = (int)((blockIdx.x * (size_t)blockDim.x + threadIdx.x) >> 6);
    if (gw >= N) return;
    const int lane = threadIdx.x & 63;
    const int j = lane & 15;
    const int w = lane >> 4;
    const int s = rowptr[gw], e = rowptr[gw + 1];

    float acc = 0.f;
    int k = s + w;
    while (k + 12 < e) {
        int2 a0 = ecv[k], a1 = ecv[k + 4], a2 = ecv[k + 8], a3 = ecv[k + 12];
        float g0 = XW[(size_t)a0.x * HID + j];
        float g1 = XW[(size_t)a1.x * HID + j];
        float g2 = XW[(size_t)a2.x * HID + j];
        float g3 = XW[(size_t)a3.x * HID + j];
        acc += __int_as_float(a0.y) * g0;
        acc += __int_as_float(a1.y) * g1;
        acc += __int_as_float(a2.y) * g2;
        acc += __int_as_float(a3.y) * g3;
        k += 16;
    }
    if (k + 4 < e) {
        int2 a0 = ecv[k], a1 = ecv[k + 4];
        acc += __int_as_float(a0.y) * XW[(size_t)a0.x * HID + j];
        acc += __int_as_float(a1.y) * XW[(size_t)a1.x * HID + j];
        k += 8;
    }
    if (k < e) {
        int2 a0 = ecv[k];
        acc += __int_as_float(a0.y) * XW[(size_t)a0.x * HID + j];
    }
    acc += __shfl_xor(acc, 16);
    acc += __shfl_xor(acc, 32);

    const float h = fmaxf(acc + b1[j], 0.f);
    float p[OUTC];
#pragma unroll
    for (int c = 0; c < OUTC; ++c) p[c] = h * W2[j * OUTC + c];
#pragma unroll
    for (int m = 1; m <= 8; m <<= 1)
#pragma unroll
        for (int c = 0; c < OUTC; ++c) p[c] += __shfl_xor(p[c], m);

    if (lane < 8) {
        float o = p[0];
        o = (lane == 1) ? p[1] : o;
        o = (lane == 2) ? p[2] : o;
        o = (lane == 3) ? p[3] : o;
        o = (lane == 4) ? p[4] : o;
        o = (lane == 5) ? p[5] : o;
        o = (lane == 6) ? p[6] : o;
        if (lane == 7) o = 0.f;           // pad col
        h2[(size_t)gw * 8 + lane] = o;
    }
}

// ---------------------------------------------------------------------------
// SpMM(7, stride-8 h2) + fused log_softmax: one wave per row.
// ---------------------------------------------------------------------------
__global__ __launch_bounds__(256) void spmm7_lsm(
    const int* __restrict__ rowptr, const int2* __restrict__ ecv,
    const float* __restrict__ h2, const float* __restrict__ b2,
    float* __restrict__ out, int N)
{
    const int gw = (int)((blockIdx.x * (size_t)blockDim.x + threadIdx.x) >> 6);
    if (gw >= N) return;
    const int lane = threadIdx.x & 63;
    const int j = lane & 7;
    const int w = lane >> 3;
    const int s = rowptr[gw], e = rowptr[gw + 1];

    float acc = 0.f;
    int k = s + w;
    while (k + 24 < e) {
        int2 a0 = ecv[k], a1 = ecv[k + 8], a2 = ecv[k + 16], a3 = ecv[k + 24];
        float g0 = h2[(size_t)a0.x * 8 + j];
        float g1 = h2[(size_t)a1.x * 8 + j];
        float g2 = h2[(size_t)a2.x * 8 + j];
        float g3 = h2[(size_t)a3.x * 8 + j];
        acc += __int_as_float(a0.y) * g0;
        acc += __int_as_float(a1.y) * g1;
        acc += __int_as_float(a2.y) * g2;
        acc += __int_as_float(a3.y) * g3;
        k += 32;
    }
    if (k + 8 < e) {
        int2 a0 = ecv[k], a1 = ecv[k + 8];
        acc += __int_as_float(a0.y) * h2[(size_t)a0.x * 8 + j];
        acc += __int_as_float(a1.y) * h2[(size_t)a1.x * 8 + j];
        k += 16;
    }
    if (k < e) {
        int2 a0 = ecv[k];
        acc += __int_as_float(a0.y) * h2[(size_t)a0.x * 8 + j];
    }
    acc += __shfl_xor(acc, 8);
    acc += __shfl_xor(acc, 16);
    acc += __shfl_xor(acc, 32);

    const float bias = b2[(j < OUTC) ? j : 0];
    const float val  = acc + bias;
    float mx = (j < OUTC) ? val : -INFINITY;
    mx = fmaxf(mx, __shfl_xor(mx, 1));
    mx = fmaxf(mx, __shfl_xor(mx, 2));
    mx = fmaxf(mx, __shfl_xor(mx, 4));
    float ex = (j < OUTC) ? expf(val - mx) : 0.f;
    ex += __shfl_xor(ex, 1);
    ex += __shfl_xor(ex, 2);
    ex += __shfl_xor(ex, 4);
    if (lane < OUTC) out[(size_t)gw * OUTC + lane] = val - mx - logf(ex);
}

// ---------------------------------------------------------------------------
// Fallback path kernels (atomic-based, used only if ws too small)
// ---------------------------------------------------------------------------
__global__ __launch_bounds__(256) void gcn_k2_spmm16_atomic(
    const int* __restrict__ arow, const int* __restrict__ acol,
    const float* __restrict__ aval, const float* __restrict__ XW,
    float* __restrict__ H, int E)
{
    int e = blockIdx.x * blockDim.x + threadIdx.x;
    if (e >= E) return;
    const int r = arow[e], c = acol[e];
    const float v = aval[e];
    const float4* src = (const float4*)(XW + (size_t)c * HID);
    float4 a = src[0], b = src[1], cc = src[2], d = src[3];
    float* dst = H + (size_t)r * HID;
    atomicAdd(dst + 0,  v * a.x);  atomicAdd(dst + 1,  v * a.y);
    atomicAdd(dst + 2,  v * a.z);  atomicAdd(dst + 3,  v * a.w);
    atomicAdd(dst + 4,  v * b.x);  atomicAdd(dst + 5,  v * b.y);
    atomicAdd(dst + 6,  v * b.z);  atomicAdd(dst + 7,  v * b.w);
    atomicAdd(dst + 8,  v * cc.x); atomicAdd(dst + 9,  v * cc.y);
    atomicAdd(dst + 10, v * cc.z); atomicAdd(dst + 11, v * cc.w);
    atomicAdd(dst + 12, v * d.x);  atomicAdd(dst + 13, v * d.y);
    atomicAdd(dst + 14, v * d.z);  atomicAdd(dst + 15, v * d.w);
}

__global__ __launch_bounds__(256) void gcn_k3_h2(
    const float* __restrict__ H, const float* __restrict__ b1,
    const float* __restrict__ W2, float* __restrict__ h2, int N)
{
    __shared__ float sW2[HID * OUTC];
    __shared__ float sb1[HID];
    if (threadIdx.x < HID * OUTC) sW2[threadIdx.x] = W2[threadIdx.x];
    if (threadIdx.x < HID)        sb1[threadIdx.x] = b1[threadIdx.x];
    __syncthreads();

    int row = blockIdx.x * blockDim.x + threadIdx.x;
    if (row >= N) return;

    const float4* hp = (const float4*)(H + (size_t)row * HID);
    float4 h0 = hp[0], h1 = hp[1], h2v = hp[2], h3 = hp[3];
    float h[16] = {h0.x, h0.y, h0.z, h0.w, h1.x, h1.y, h1.z, h1.w,
                   h2v.x, h2v.y, h2v.z, h2v.w, h3.x, h3.y, h3.z, h3.w};
#pragma unroll
    for (int i = 0; i < HID; ++i) {
        h[i] += sb1[i];
        h[i] = h[i] > 0.f ? h[i] : 0.f;
    }
    float o[8];
#pragma unroll
    for (int jj = 0; jj < OUTC; ++jj) {
        float sum = 0.f;
#pragma unroll
        for (int i = 0; i < HID; ++i) sum += h[i] * sW2[i * OUTC + jj];
        o[jj] = sum;
    }
    o[7] = 0.f;
    float4* op = (float4*)(h2 + (size_t)row * 8);
    op[0] = make_float4(o[0], o[1], o[2], o[3]);
    op[1] = make_float4(o[4], o[5], o[6], o[7]);
}

__global__ __launch_bounds__(256) void gcn_k4_spmm7_atomic(
    const int* __restrict__ arow, const int* __restrict__ acol,
    const float* __restrict__ aval, const float* __restrict__ h2,
    float* __restrict__ out, int E)
{
    int e = blockIdx.x * blockDim.x + threadIdx.x;
    if (e >= E) return;
    const int r = arow[e], c = acol[e];
    const float v = aval[e];
    const float* src = h2 + (size_t)c * 8;
    float* dst = out + (size_t)r * OUTC;
#pragma unroll
    for (int jj = 0; jj < OUTC; ++jj) atomicAdd(dst + jj, v * src[jj]);
}

__global__ __launch_bounds__(256) void gcn_k5_lsm(
    float* __restrict__ out, const float* __restrict__ b2, int N)
{
    int row = blockIdx.x * blockDim.x + threadIdx.x;
    if (row >= N) return;
    float* p = out + (size_t)row * OUTC;
    float v[OUTC];
#pragma unroll
    for (int jj = 0; jj < OUTC; ++jj) v[jj] = p[jj] + b2[jj];
    float m = v[0];
#pragma unroll
    for (int jj = 1; jj < OUTC; ++jj) m = fmaxf(m, v[jj]);
    float s = 0.f;
#pragma unroll
    for (int jj = 0; jj < OUTC; ++jj) s += expf(v[jj] - m);
    const float ls = logf(s);
#pragma unroll
    for (int jj = 0; jj < OUTC; ++jj) p[jj] = v[jj] - m - ls;
}

// ---------------------------------------------------------------------------
extern "C" void kernel_launch(void* const* d_in, const int* in_sizes, int n_in,
                              void* d_out, int out_size, void* d_ws, size_t ws_size,
                              hipStream_t stream)
{
    const float* x    = (const float*)d_in[0];
    const int*   arow = (const int*)d_in[1];
    const int*   acol = (const int*)d_in[2];
    const float* aval = (const float*)d_in[3];
    const float* W1   = (const float*)d_in[4];
    const float* b1   = (const float*)d_in[5];
    const float* W2   = (const float*)d_in[6];
    const float* b2   = (const float*)d_in[7];
    float* out = (float*)d_out;

    const int N = in_sizes[0] / IN_F;
    const int E = in_sizes[1];

    // fast-path ws layout (all chunks 16B-aligned):
    // [ecv E*8] [XW N*16f] [h2 N*8f] [cnt Np4] [cursor Np4] [rowptr Np4+4]
    const int Np4 = (N + 3) & ~3;
    char* wsp = (char*)d_ws;
    int2*  ecv    = (int2*)wsp;   wsp += (size_t)E * 8;
    float* XW     = (float*)wsp;  wsp += (size_t)N * HID * 4;
    float* h2     = (float*)wsp;  wsp += (size_t)N * 8 * 4;
    int*   cnt    = (int*)wsp;    wsp += (size_t)Np4 * 4;
    int*   cursor = (int*)wsp;    wsp += (size_t)Np4 * 4;
    int*   rowptr = (int*)wsp;    wsp += (size_t)(Np4 + 4) * 4;
    const size_t need = (size_t)(wsp - (char*)d_ws);

    const int eb = (E + 255) / 256;
    const int nb = (N + 255) / 256;
    const int k1b = (N + K1_ROWS_B - 1) / K1_ROWS_B;

    if (ws_size >= need) {
        // ---- fast path: CSR + gather SpMM, no fp atomics, K3 fused ----
        const int n4 = Np4 / 4;
        zero_i32<<<(n4 + 255) / 256, 256, 0, stream>>>((int4*)cnt, n4);
        csr_hist<<<2048, 256, 0, stream>>>(arow, cnt, E);
        csr_scan<<<1, SCAN_T, 0, stream>>>(cnt, rowptr, cursor, N);
        csr_scatter<<<2048, 256, 0, stream>>>(arow, acol, aval, cursor, ecv, E);

        gcn_k1_xw<<<k1b, K1_THREADS, 0, stream>>>(x, W1, XW, N);
        spmm16_h2<<<(N + 3) / 4, 256, 0, stream>>>(rowptr, ecv, XW, b1, W2, h2, N);
        spmm7_lsm<<<(N + 3) / 4, 256, 0, stream>>>(rowptr, ecv, h2, b2, out, N);
    } else {
        // ---- fallback: atomic path (needs only XW+H = 12.8 MB) ----
        float* XWf = (float*)d_ws;
        float* Hf  = XWf + (size_t)N * HID;
        float* h2f = XWf;   // XW dead after spmm16_atomic
        const int hz4 = (int)(((size_t)N * HID) / 4);
        zero_i32<<<(hz4 + 255) / 256, 256, 0, stream>>>((int4*)Hf, hz4);
        hipMemsetAsync(out, 0, (size_t)N * OUTC * sizeof(float), stream);
        gcn_k1_xw<<<k1b, K1_THREADS, 0, stream>>>(x, W1, XWf, N);
        gcn_k2_spmm16_atomic<<<eb, 256, 0, stream>>>(arow, acol, aval, XWf, Hf, E);
        gcn_k3_h2<<<nb, 256, 0, stream>>>(Hf, b1, W2, h2f, N);
        gcn_k4_spmm7_atomic<<<eb, 256, 0, stream>>>(arow, acol, aval, h2f, out, E);
        gcn_k5_lsm<<<nb, 256, 0, stream>>>(out, b2, N);
    }
}

// Round 8
// 552.952 us; speedup vs baseline: 1.7161x; 1.3477x over previous
//
#include <hip/hip_runtime.h>
#include <math.h>

#define IN_F 1433
#define HID  16
#define OUTC 7
#define SCAN_T 1024

// K1 geometry
#define K1_THREADS 512        // 8 waves
#define K1_ROWS_W  8          // rows per wave
#define K1_ROWS_B  64         // rows per block
#define KA         768        // phase-A k count
#define LDSW       17         // padded LDS row stride (words)
#define K1_LDS_FLOATS (KA * LDSW)   // 13056 floats = 52224 B

__host__ __device__ __forceinline__ int imin(int a, int b) { return a < b ? a : b; }

// ---------------------------------------------------------------------------
// zero_i32: cheap in-graph zeroing
// ---------------------------------------------------------------------------
__global__ __launch_bounds__(256) void zero_i32(int4* __restrict__ p, int n4)
{
    int i = blockIdx.x * blockDim.x + threadIdx.x;
    if (i < n4) p[i] = make_int4(0, 0, 0, 0);
}

// ---------------------------------------------------------------------------
// K1 body: XW = x @ W1 with W1 staged in LDS (two phases).
// lane = j4*16 + ks. NO wave-level early return: every thread must help
// stage W1 (early-exit waves previously left LDS unstaged - latent bug).
// ---------------------------------------------------------------------------
__device__ __forceinline__ void k1_body(
    const float* __restrict__ x, const float* __restrict__ W1,
    float* __restrict__ XW, int N, int vbid, float* sW)
{
    const int wave = threadIdx.x >> 6;
    const int lane = threadIdx.x & 63;
    const int ks   = lane & 15;
    const int j4   = lane >> 4;
    const int row0 = vbid * K1_ROWS_B + wave * K1_ROWS_W;

    size_t xoff[K1_ROWS_W];
#pragma unroll
    for (int r = 0; r < K1_ROWS_W; ++r) {
        int row = row0 + r;
        if (row > N - 1) row = N - 1;       // clamp; store masked later
        if (row < 0) row = 0;
        xoff[r] = (size_t)row * IN_F;
    }

    float acc[K1_ROWS_W][4];
#pragma unroll
    for (int r = 0; r < K1_ROWS_W; ++r)
#pragma unroll
        for (int jj = 0; jj < 4; ++jj) acc[r][jj] = 0.f;

    // ---------------- phase A: k in [0, KA) ----------------
    for (int f = threadIdx.x; f < KA * HID; f += K1_THREADS)
        sW[(f >> 4) * LDSW + (f & 15)] = W1[f];
    __syncthreads();

#pragma unroll 2
    for (int c = 0; c < KA / 16; ++c) {
        const int kloc = c * 16 + ks;
        const float* wr = sW + (size_t)kloc * LDSW + j4 * 4;
        float w0 = wr[0], w1 = wr[1], w2 = wr[2], w3 = wr[3];
        const int k = kloc;
        float xv[K1_ROWS_W];
#pragma unroll
        for (int r = 0; r < K1_ROWS_W; ++r) xv[r] = x[xoff[r] + k];
#pragma unroll
        for (int r = 0; r < K1_ROWS_W; ++r) {
            acc[r][0] += xv[r] * w0;
            acc[r][1] += xv[r] * w1;
            acc[r][2] += xv[r] * w2;
            acc[r][3] += xv[r] * w3;
        }
    }
    __syncthreads();

    // ---------------- phase B: k in [KA, IN_F) ----------------
    for (int f = threadIdx.x; f < (IN_F - KA) * HID; f += K1_THREADS)
        sW[(f >> 4) * LDSW + (f & 15)] = W1[KA * HID + f];
    __syncthreads();

    const int NB_CHUNKS = (IN_F - KA + 15) / 16;   // 42, last partial
#pragma unroll 2
    for (int c = 0; c < NB_CHUNKS; ++c) {
        const int kloc = c * 16 + ks;
        const int k = KA + kloc;
        const bool ok = (k < IN_F);
        const float* wr = sW + (size_t)kloc * LDSW + j4 * 4;
        float w0 = wr[0], w1 = wr[1], w2 = wr[2], w3 = wr[3];
        float xv[K1_ROWS_W];
#pragma unroll
        for (int r = 0; r < K1_ROWS_W; ++r)
            xv[r] = ok ? x[xoff[r] + k] : 0.f;     // 0 * stale-w == 0
#pragma unroll
        for (int r = 0; r < K1_ROWS_W; ++r) {
            acc[r][0] += xv[r] * w0;
            acc[r][1] += xv[r] * w1;
            acc[r][2] += xv[r] * w2;
            acc[r][3] += xv[r] * w3;
        }
    }

    // butterfly over the 16 ks-lanes (lane bits 0..3)
#pragma unroll
    for (int m = 1; m <= 8; m <<= 1)
#pragma unroll
        for (int r = 0; r < K1_ROWS_W; ++r)
#pragma unroll
            for (int jj = 0; jj < 4; ++jj)
                acc[r][jj] += __shfl_xor(acc[r][jj], m);

    if (ks == 0) {
#pragma unroll
        for (int r = 0; r < K1_ROWS_W; ++r) {
            const int row = row0 + r;
            if (row >= 0 && row < N) {
                float4 o = make_float4(acc[r][0], acc[r][1], acc[r][2], acc[r][3]);
                *(float4*)(XW + (size_t)row * HID + j4 * 4) = o;
            }
        }
    }
}

// ---------------------------------------------------------------------------
// hist / scatter bodies (grid-strided over a virtual sub-grid)
// ---------------------------------------------------------------------------
__device__ __forceinline__ void hist_body(
    const int* __restrict__ arow, int* __restrict__ cnt, int E, int hb, int nhb)
{
    const int tid = hb * K1_THREADS + threadIdx.x;
    const int stride = nhb * K1_THREADS;
    const int E4 = E >> 2;
    const int4* a4 = (const int4*)arow;
    for (int v = tid; v < E4; v += stride) {
        int4 r = a4[v];
        atomicAdd(&cnt[r.x], 1);
        atomicAdd(&cnt[r.y], 1);
        atomicAdd(&cnt[r.z], 1);
        atomicAdd(&cnt[r.w], 1);
    }
    for (int v = E4 * 4 + tid; v < E; v += stride) atomicAdd(&cnt[arow[v]], 1);
}

__device__ __forceinline__ void scatter_body(
    const int* __restrict__ arow, const int* __restrict__ acol,
    const float* __restrict__ aval, int* __restrict__ cursor,
    int2* __restrict__ ecv, int E, int sb, int nsb)
{
    const int tid = sb * K1_THREADS + threadIdx.x;
    const int stride = nsb * K1_THREADS;
    const int E4 = E >> 2;
    const int4*   ar4 = (const int4*)arow;
    const int4*   ac4 = (const int4*)acol;
    const float4* av4 = (const float4*)aval;
    for (int v = tid; v < E4; v += stride) {
        int4 r = ar4[v];
        int4 c = ac4[v];
        float4 val = av4[v];
        int p0 = atomicAdd(&cursor[r.x], 1);
        int p1 = atomicAdd(&cursor[r.y], 1);
        int p2 = atomicAdd(&cursor[r.z], 1);
        int p3 = atomicAdd(&cursor[r.w], 1);
        ecv[p0] = make_int2(c.x, __float_as_int(val.x));
        ecv[p1] = make_int2(c.y, __float_as_int(val.y));
        ecv[p2] = make_int2(c.z, __float_as_int(val.z));
        ecv[p3] = make_int2(c.w, __float_as_int(val.w));
    }
    for (int v = E4 * 4 + tid; v < E; v += stride) {
        int pos = atomicAdd(&cursor[arow[v]], 1);
        ecv[pos] = make_int2(acol[v], __float_as_int(aval[v]));
    }
}

// ---------------------------------------------------------------------------
// Fat kernels: K1 halves overlapped with hist / scatter (independent work
// fused into one dispatch; can't fork streams under graph capture).
// Every 3rd block (bid%3==2, first `aux` of them) does the aux role.
// ---------------------------------------------------------------------------
__global__ __launch_bounds__(K1_THREADS) void k1_hist_fused(
    const float* __restrict__ x, const float* __restrict__ W1,
    float* __restrict__ XW, int N, int half1,
    const int* __restrict__ arow, int* __restrict__ cnt, int E, int histB)
{
    __shared__ float sW[K1_LDS_FLOATS];
    const int bid = blockIdx.x;
    if ((bid % 3 == 2) && (bid / 3 < histB)) {
        hist_body(arow, cnt, E, bid / 3, histB);
        return;
    }
    const int k1_idx = bid - imin((bid + 1) / 3, histB);
    if (k1_idx >= half1) return;
    k1_body(x, W1, XW, N, k1_idx, sW);
}

__global__ __launch_bounds__(K1_THREADS) void k1_scatter_fused(
    const float* __restrict__ x, const float* __restrict__ W1,
    float* __restrict__ XW, int N, int half1, int half2,
    const int* __restrict__ arow, const int* __restrict__ acol,
    const float* __restrict__ aval, int* __restrict__ cursor,
    int2* __restrict__ ecv, int E, int scb)
{
    __shared__ float sW[K1_LDS_FLOATS];
    const int bid = blockIdx.x;
    if ((bid % 3 == 2) && (bid / 3 < scb)) {
        scatter_body(arow, acol, aval, cursor, ecv, E, bid / 3, scb);
        return;
    }
    const int k1_idx = bid - imin((bid + 1) / 3, scb) + half1;
    if (k1_idx >= half1 + half2) return;
    k1_body(x, W1, XW, N, k1_idx, sW);
}

// plain K1 wrapper (fallback / degenerate paths)
__global__ __launch_bounds__(K1_THREADS) void gcn_k1_xw(
    const float* __restrict__ x, const float* __restrict__ W1,
    float* __restrict__ XW, int N)
{
    __shared__ float sW[K1_LDS_FLOATS];
    k1_body(x, W1, XW, N, blockIdx.x, sW);
}

// plain hist / scatter (degenerate tiny-N path)
__global__ __launch_bounds__(256) void csr_hist(
    const int* __restrict__ arow, int* __restrict__ cnt, int E)
{
    int e = blockIdx.x * blockDim.x + threadIdx.x;
    if (e < E) atomicAdd(&cnt[arow[e]], 1);
}

__global__ __launch_bounds__(256) void csr_scatter(
    const int* __restrict__ arow, const int* __restrict__ acol,
    const float* __restrict__ aval, int* __restrict__ cursor,
    int2* __restrict__ ecv, int E)
{
    int e = blockIdx.x * blockDim.x + threadIdx.x;
    if (e >= E) return;
    int pos = atomicAdd(&cursor[arow[e]], 1);
    ecv[pos] = make_int2(acol[e], __float_as_int(aval[e]));
}

// ---------------------------------------------------------------------------
// csr_scan: single-block scan. Row starts rounded UP TO EVEN so that every
// CSR row segment begins 16B-aligned in ecv (enables dwordx4 edge loads).
// Pad slots are pre-zeroed (bulk ecv zero) -> val=0, col=0: harmless.
// ---------------------------------------------------------------------------
__global__ __launch_bounds__(SCAN_T) void csr_scan(
    const int* __restrict__ cnt, int* __restrict__ rowptr,
    int* __restrict__ cursor, int N)
{
    __shared__ int sums[SCAN_T];
    const int t = threadIdx.x;
    const int chunk = (((N + SCAN_T - 1) / SCAN_T) + 3) & ~3;  // 4-aligned
    const int lo = t * chunk;
    int s = 0;
    const bool full = (lo + chunk <= N);
    if (full) {
        const int4* c4 = (const int4*)(cnt + lo);
#pragma unroll 4
        for (int i = 0; i < chunk / 4; ++i) {
            int4 v = c4[i];
            s += ((v.x + 1) & ~1) + ((v.y + 1) & ~1)
               + ((v.z + 1) & ~1) + ((v.w + 1) & ~1);
        }
    } else {
        const int hi = (lo + chunk < N) ? lo + chunk : N;
        for (int i = lo; i < hi; ++i) s += (cnt[i] + 1) & ~1;
    }
    sums[t] = s;
    __syncthreads();
    for (int d = 1; d < SCAN_T; d <<= 1) {
        int a = sums[t];
        int b = (t >= d) ? sums[t - d] : 0;
        __syncthreads();
        sums[t] = a + b;
        __syncthreads();
    }
    int run = sums[t] - s;  // exclusive prefix (padded)
    if (full) {
        const int4* c4 = (const int4*)(cnt + lo);
        int4* rp4 = (int4*)(rowptr + lo);
        int4* cu4 = (int4*)(cursor + lo);
        for (int i = 0; i < chunk / 4; ++i) {
            int4 v = c4[i];
            int4 o;
            o.x = run; run += (v.x + 1) & ~1;
            o.y = run; run += (v.y + 1) & ~1;
            o.z = run; run += (v.z + 1) & ~1;
            o.w = run; run += (v.w + 1) & ~1;
            rp4[i] = o;
            cu4[i] = o;
        }
    } else {
        const int hi = (lo + chunk < N) ? lo + chunk : N;
        for (int i = lo; i < hi; ++i) {
            rowptr[i] = run;
            cursor[i] = run;
            run += (cnt[i] + 1) & ~1;
        }
    }
    if (t == SCAN_T - 1) rowptr[N] = sums[SCAN_T - 1];
}

// ---------------------------------------------------------------------------
// SpMM(16) + relu(.+b1) @ W2 fused: one wave per row, 4 ways x 16 cols.
// Each way owns 4 CONTIGUOUS edges per iteration -> 2 aligned dwordx4 loads.
// ---------------------------------------------------------------------------
__global__ __launch_bounds__(256) void spmm16_h2(
    const int* __restrict__ rowptr, const int2* __restrict__ ecv,
    const float* __restrict__ XW, const float* __restrict__ b1,
    const float* __restrict__ W2, float* __restrict__ h2, int N)
{
    const int gw = (int)((blockIdx.x * (size_t)blockDim.x + threadIdx.x) >> 6);
    if (gw >= N) return;
    const int lane = threadIdx.x & 63;
    const int j = lane & 15;
    const int w = lane >> 4;
    const int s = rowptr[gw], e = rowptr[gw + 1];   // s,e even

    float acc = 0.f;
    int k = s + w * 4;
    while (k + 4 <= e) {
        const int4* q = (const int4*)(ecv + k);     // k even -> 16B aligned
        int4 A = q[0], B = q[1];
        float g0 = XW[(size_t)A.x * HID + j];
        float g1 = XW[(size_t)A.z * HID + j];
        float g2 = XW[(size_t)B.x * HID + j];
        float g3 = XW[(size_t)B.z * HID + j];
        acc += __int_as_float(A.y) * g0;
        acc += __int_as_float(A.w) * g1;
        acc += __int_as_float(B.y) * g2;
        acc += __int_as_float(B.w) * g3;
        k += 16;
    }
    for (; k < e; ++k) {                            // <=3 leftover this way
        int2 a = ecv[k];
        acc += __int_as_float(a.y) * XW[(size_t)a.x * HID + j];
    }
    // reduce the 4 edge-ways (lane bits 4,5)
    acc += __shfl_xor(acc, 16);
    acc += __shfl_xor(acc, 32);

    // fused layer-2 projection
    const float h = fmaxf(acc + b1[j], 0.f);
    float p[OUTC];
#pragma unroll
    for (int c = 0; c < OUTC; ++c) p[c] = h * W2[j * OUTC + c];
#pragma unroll
    for (int m = 1; m <= 8; m <<= 1)
#pragma unroll
        for (int c = 0; c < OUTC; ++c) p[c] += __shfl_xor(p[c], m);

    if (lane < 8) {
        float o = p[0];
        o = (lane == 1) ? p[1] : o;
        o = (lane == 2) ? p[2] : o;
        o = (lane == 3) ? p[3] : o;
        o = (lane == 4) ? p[4] : o;
        o = (lane == 5) ? p[5] : o;
        o = (lane == 6) ? p[6] : o;
        if (lane == 7) o = 0.f;           // pad col
        h2[(size_t)gw * 8 + lane] = o;
    }
}

// ---------------------------------------------------------------------------
// SpMM(7, stride-8 h2) + fused log_softmax: one wave per row, 8 ways x 8 cols.
// ---------------------------------------------------------------------------
__global__ __launch_bounds__(256) void spmm7_lsm(
    const int* __restrict__ rowptr, const int2* __restrict__ ecv,
    const float* __restrict__ h2, const float* __restrict__ b2,
    float* __restrict__ out, int N)
{
    const int gw = (int)((blockIdx.x * (size_t)blockDim.x + threadIdx.x) >> 6);
    if (gw >= N) return;
    const int lane = threadIdx.x & 63;
    const int j = lane & 7;
    const int w = lane >> 3;
    const int s = rowptr[gw], e = rowptr[gw + 1];

    float acc = 0.f;
    int k = s + w * 4;
    while (k + 4 <= e) {
        const int4* q = (const int4*)(ecv + k);
        int4 A = q[0], B = q[1];
        float g0 = h2[(size_t)A.x * 8 + j];
        float g1 = h2[(size_t)A.z * 8 + j];
        float g2 = h2[(size_t)B.x * 8 + j];
        float g3 = h2[(size_t)B.z * 8 + j];
        acc += __int_as_float(A.y) * g0;
        acc += __int_as_float(A.w) * g1;
        acc += __int_as_float(B.y) * g2;
        acc += __int_as_float(B.w) * g3;
        k += 32;
    }
    for (; k < e; ++k) {
        int2 a = ecv[k];
        acc += __int_as_float(a.y) * h2[(size_t)a.x * 8 + j];
    }
    // reduce the 8 edge-ways (lane bits 3,4,5)
    acc += __shfl_xor(acc, 8);
    acc += __shfl_xor(acc, 16);
    acc += __shfl_xor(acc, 32);

    const float bias = b2[(j < OUTC) ? j : 0];
    const float val  = acc + bias;
    float mx = (j < OUTC) ? val : -INFINITY;
    mx = fmaxf(mx, __shfl_xor(mx, 1));
    mx = fmaxf(mx, __shfl_xor(mx, 2));
    mx = fmaxf(mx, __shfl_xor(mx, 4));
    float ex = (j < OUTC) ? expf(val - mx) : 0.f;
    ex += __shfl_xor(ex, 1);
    ex += __shfl_xor(ex, 2);
    ex += __shfl_xor(ex, 4);
    if (lane < OUTC) out[(size_t)gw * OUTC + lane] = val - mx - logf(ex);
}

// ---------------------------------------------------------------------------
// Fallback path kernels (atomic-based, used only if ws too small)
// ---------------------------------------------------------------------------
__global__ __launch_bounds__(256) void gcn_k2_spmm16_atomic(
    const int* __restrict__ arow, const int* __restrict__ acol,
    const float* __restrict__ aval, const float* __restrict__ XW,
    float* __restrict__ H, int E)
{
    int e = blockIdx.x * blockDim.x + threadIdx.x;
    if (e >= E) return;
    const int r = arow[e], c = acol[e];
    const float v = aval[e];
    const float4* src = (const float4*)(XW + (size_t)c * HID);
    float4 a = src[0], b = src[1], cc = src[2], d = src[3];
    float* dst = H + (size_t)r * HID;
    atomicAdd(dst + 0,  v * a.x);  atomicAdd(dst + 1,  v * a.y);
    atomicAdd(dst + 2,  v * a.z);  atomicAdd(dst + 3,  v * a.w);
    atomicAdd(dst + 4,  v * b.x);  atomicAdd(dst + 5,  v * b.y);
    atomicAdd(dst + 6,  v * b.z);  atomicAdd(dst + 7,  v * b.w);
    atomicAdd(dst + 8,  v * cc.x); atomicAdd(dst + 9,  v * cc.y);
    atomicAdd(dst + 10, v * cc.z); atomicAdd(dst + 11, v * cc.w);
    atomicAdd(dst + 12, v * d.x);  atomicAdd(dst + 13, v * d.y);
    atomicAdd(dst + 14, v * d.z);  atomicAdd(dst + 15, v * d.w);
}

__global__ __launch_bounds__(256) void gcn_k3_h2(
    const float* __restrict__ H, const float* __restrict__ b1,
    const float* __restrict__ W2, float* __restrict__ h2, int N)
{
    __shared__ float sW2[HID * OUTC];
    __shared__ float sb1[HID];
    if (threadIdx.x < HID * OUTC) sW2[threadIdx.x] = W2[threadIdx.x];
    if (threadIdx.x < HID)        sb1[threadIdx.x] = b1[threadIdx.x];
    __syncthreads();

    int row = blockIdx.x * blockDim.x + threadIdx.x;
    if (row >= N) return;

    const float4* hp = (const float4*)(H + (size_t)row * HID);
    float4 h0 = hp[0], h1 = hp[1], h2v = hp[2], h3 = hp[3];
    float h[16] = {h0.x, h0.y, h0.z, h0.w, h1.x, h1.y, h1.z, h1.w,
                   h2v.x, h2v.y, h2v.z, h2v.w, h3.x, h3.y, h3.z, h3.w};
#pragma unroll
    for (int i = 0; i < HID; ++i) {
        h[i] += sb1[i];
        h[i] = h[i] > 0.f ? h[i] : 0.f;
    }
    float o[8];
#pragma unroll
    for (int jj = 0; jj < OUTC; ++jj) {
        float sum = 0.f;
#pragma unroll
        for (int i = 0; i < HID; ++i) sum += h[i] * sW2[i * OUTC + jj];
        o[jj] = sum;
    }
    o[7] = 0.f;
    float4* op = (float4*)(h2 + (size_t)row * 8);
    op[0] = make_float4(o[0], o[1], o[2], o[3]);
    op[1] = make_float4(o[4], o[5], o[6], o[7]);
}

__global__ __launch_bounds__(256) void gcn_k4_spmm7_atomic(
    const int* __restrict__ arow, const int* __restrict__ acol,
    const float* __restrict__ aval, const float* __restrict__ h2,
    float* __restrict__ out, int E)
{
    int e = blockIdx.x * blockDim.x + threadIdx.x;
    if (e >= E) return;
    const int r = arow[e], c = acol[e];
    const float v = aval[e];
    const float* src = h2 + (size_t)c * 8;
    float* dst = out + (size_t)r * OUTC;
#pragma unroll
    for (int jj = 0; jj < OUTC; ++jj) atomicAdd(dst + jj, v * src[jj]);
}

__global__ __launch_bounds__(256) void gcn_k5_lsm(
    float* __restrict__ out, const float* __restrict__ b2, int N)
{
    int row = blockIdx.x * blockDim.x + threadIdx.x;
    if (row >= N) return;
    float* p = out + (size_t)row * OUTC;
    float v[OUTC];
#pragma unroll
    for (int jj = 0; jj < OUTC; ++jj) v[jj] = p[jj] + b2[jj];
    float m = v[0];
#pragma unroll
    for (int jj = 1; jj < OUTC; ++jj) m = fmaxf(m, v[jj]);
    float s = 0.f;
#pragma unroll
    for (int jj = 0; jj < OUTC; ++jj) s += expf(v[jj] - m);
    const float ls = logf(s);
#pragma unroll
    for (int jj = 0; jj < OUTC; ++jj) p[jj] = v[jj] - m - ls;
}

// ---------------------------------------------------------------------------
extern "C" void kernel_launch(void* const* d_in, const int* in_sizes, int n_in,
                              void* d_out, int out_size, void* d_ws, size_t ws_size,
                              hipStream_t stream)
{
    const float* x    = (const float*)d_in[0];
    const int*   arow = (const int*)d_in[1];
    const int*   acol = (const int*)d_in[2];
    const float* aval = (const float*)d_in[3];
    const float* W1   = (const float*)d_in[4];
    const float* b1   = (const float*)d_in[5];
    const float* W2   = (const float*)d_in[6];
    const float* b2   = (const float*)d_in[7];
    float* out = (float*)d_out;

    const int N = in_sizes[0] / IN_F;
    const int E = in_sizes[1];

    // fast-path ws layout (16B-aligned chunks). ecv sized E+N (row padding);
    // [ecv | cnt] is one contiguous zero span.
    const int Np4  = (N + 3) & ~3;
    const int EPAD = E + N + 8;
    char* wsp = (char*)d_ws;
    int2*  ecv    = (int2*)wsp;   wsp += (size_t)EPAD * 8;
    int*   cnt    = (int*)wsp;    wsp += (size_t)Np4 * 4;
    int*   cursor = (int*)wsp;    wsp += (size_t)Np4 * 4;
    int*   rowptr = (int*)wsp;    wsp += (size_t)(Np4 + 4) * 4;
    float* XW     = (float*)wsp;  wsp += (size_t)N * HID * 4;
    float* h2     = (float*)wsp;  wsp += (size_t)N * 8 * 4;
    const size_t need = (size_t)(wsp - (char*)d_ws);

    const int eb  = (E + 255) / 256;
    const int nb  = (N + 255) / 256;
    const int k1b = (N + K1_ROWS_B - 1) / K1_ROWS_B;

    if (ws_size >= need) {
        // zero span: ecv + cnt (pads in ecv must be 0: val=0 -> no contribution)
        const size_t zbytes = (size_t)EPAD * 8 + (size_t)Np4 * 4;
        const int n4z = (int)((zbytes + 15) / 16);
        zero_i32<<<(n4z + 255) / 256, 256, 0, stream>>>((int4*)d_ws, n4z);

        const int half1 = (k1b + 1) / 2;
        const int half2 = k1b - half1;
        const int histB = imin(384, half1 / 2);
        const int scb   = imin(384, half2 / 2);

        if (histB >= 1 && scb >= 1) {
            // [K1 half1 || hist] -> scan -> [K1 half2 || scatter]
            k1_hist_fused<<<half1 + histB, K1_THREADS, 0, stream>>>(
                x, W1, XW, N, half1, arow, cnt, E, histB);
            csr_scan<<<1, SCAN_T, 0, stream>>>(cnt, rowptr, cursor, N);
            k1_scatter_fused<<<half2 + scb, K1_THREADS, 0, stream>>>(
                x, W1, XW, N, half1, half2, arow, acol, aval, cursor, ecv, E, scb);
        } else {
            // tiny N: plain sequential
            csr_hist<<<eb, 256, 0, stream>>>(arow, cnt, E);
            csr_scan<<<1, SCAN_T, 0, stream>>>(cnt, rowptr, cursor, N);
            csr_scatter<<<eb, 256, 0, stream>>>(arow, acol, aval, cursor, ecv, E);
            gcn_k1_xw<<<k1b, K1_THREADS, 0, stream>>>(x, W1, XW, N);
        }

        spmm16_h2<<<(N + 3) / 4, 256, 0, stream>>>(rowptr, ecv, XW, b1, W2, h2, N);
        spmm7_lsm<<<(N + 3) / 4, 256, 0, stream>>>(rowptr, ecv, h2, b2, out, N);
    } else {
        // ---- fallback: atomic path (needs only XW+H = 12.8 MB) ----
        float* XWf = (float*)d_ws;
        float* Hf  = XWf + (size_t)N * HID;
        float* h2f = XWf;   // XW dead after spmm16_atomic
        const int hz4 = (int)(((size_t)N * HID) / 4);
        zero_i32<<<(hz4 + 255) / 256, 256, 0, stream>>>((int4*)Hf, hz4);
        (void)hipMemsetAsync(out, 0, (size_t)N * OUTC * sizeof(float), stream);
        gcn_k1_xw<<<k1b, K1_THREADS, 0, stream>>>(x, W1, XWf, N);
        gcn_k2_spmm16_atomic<<<eb, 256, 0, stream>>>(arow, acol, aval, XWf, Hf, E);
        gcn_k3_h2<<<nb, 256, 0, stream>>>(Hf, b1, W2, h2f, N);
        gcn_k4_spmm7_atomic<<<eb, 256, 0, stream>>>(arow, acol, aval, h2f, out, E);
        gcn_k5_lsm<<<nb, 256, 0, stream>>>(out, b2, N);
    }
}